// Round 16
// baseline (247.539 us; speedup 1.0000x reference)
//
#include <hip/hip_runtime.h>
#include <hip/hip_bf16.h>

// Problem constants (B,S,D,H,KVH,HD) = (2,2048,2048,16,8,128)
#define B_   2
#define S_   2048
#define D_   2048
#define H_   16
#define KVH_ 8
#define HD_  128
#define TOK_ (B_ * S_)        // 4096 rows
#define KVSZ_ (KVH_ * HD_ * D_)
#define SCALE_LOG2E_ (0.08838834764831845f * 1.4426950408889634f)

typedef __bf16 bf16_t;
typedef bf16_t bf16x8 __attribute__((ext_vector_type(8)));
typedef bf16_t bf16x4 __attribute__((ext_vector_type(4)));
typedef float  f32x4  __attribute__((ext_vector_type(4)));
typedef unsigned int u32x4 __attribute__((ext_vector_type(4)));

#if __has_builtin(__builtin_amdgcn_exp2f)
#define EXP2F(x) __builtin_amdgcn_exp2f(x)
#else
#define EXP2F(x) exp2f(x)
#endif

// async global->LDS, 16B per lane (LDS dest = wave-uniform base + lane*16)
__device__ __forceinline__ void gload16(const bf16_t* g, bf16_t* l) {
    auto* gp = (const __attribute__((address_space(1))) unsigned int*)(g);
    auto* lp = (__attribute__((address_space(3))) unsigned int*)(l);
    __builtin_amdgcn_global_load_lds(gp, lp, 16, 0, 0);
}

// well-defined pull: dst[l] = src[byte_index[l] >> 2]
__device__ __forceinline__ unsigned bperm(int lane_bytes, unsigned src) {
    return (unsigned)__builtin_amdgcn_ds_bpermute(lane_bytes, (int)src);
}

// ---------------------------------------------------------------- fused pre-pass
// One launch: f32->bf16 converts (x, Wq|Wk|Wv packed, Wo) + RoPE tables.
// All region sizes are multiples of 1024 elements -> each 256-thread block
// (1024 elems) lies entirely in one region; branches are wave-uniform.
#define CVT_BLKS_ ((TOK_ * D_ + 2 * D_ * D_ + 2 * KVSZ_) / 1024)
__global__ __launch_bounds__(256) void fused_pre(const float* __restrict__ x,
                                                 const float* __restrict__ Wq,
                                                 const float* __restrict__ Wk,
                                                 const float* __restrict__ Wv,
                                                 const float* __restrict__ Wo,
                                                 bf16_t* __restrict__ xb,
                                                 bf16_t* __restrict__ wqkvb,
                                                 bf16_t* __restrict__ wob,
                                                 float* __restrict__ ct,
                                                 float* __restrict__ st) {
    int bid = blockIdx.x;
    if (bid < CVT_BLKS_) {
        size_t i = (size_t)bid * 1024 + (size_t)threadIdx.x * 4;
        const size_t c0 = (size_t)TOK_ * D_;
        const size_t c1 = c0 + (size_t)D_ * D_;
        const size_t c2 = c1 + (size_t)KVSZ_;
        const size_t c3 = c2 + (size_t)KVSZ_;
        const float* src;
        bf16_t* dst;
        if (i < c0)      { src = x  + i;        dst = xb + i; }
        else if (i < c1) { src = Wq + (i - c0); dst = wqkvb + (i - c0); }
        else if (i < c2) { src = Wk + (i - c1); dst = wqkvb + (size_t)D_ * D_ + (i - c1); }
        else if (i < c3) { src = Wv + (i - c2); dst = wqkvb + (size_t)D_ * D_ + KVSZ_ + (i - c2); }
        else             { src = Wo + (i - c3); dst = wob + (i - c3); }
        float4 v = *(const float4*)src;
        bf16x4 o;
        o[0] = (bf16_t)v.x; o[1] = (bf16_t)v.y; o[2] = (bf16_t)v.z; o[3] = (bf16_t)v.w;
        *(bf16x4*)dst = o;
    } else {
        int i = (bid - CVT_BLKS_) * 256 + threadIdx.x;   // < S_*64
        int s = i >> 6, j = i & 63;
        float ang = (float)s * exp2f(-(float)j * 0.20762050593046013f);
        float si, co;
        sincosf(ang, &si, &co);
        ct[i] = co;
        st[i] = si;
    }
}

// ---------------------------------------------------------------- GEMM C = A * B^T
// Depth-2 / 3-buffer counted-vmcnt pipeline (T4): raw s_barrier + vmcnt(4)
// (never 0 mid-loop) -> the next tile's loads stay in flight ACROSS the
// barrier and get two compute phases to land. BK=32, ^(r&3) chunk swizzle.
template <typename OutT>
__global__ __launch_bounds__(256) void gemm_bt(const bf16_t* __restrict__ A,
                                               const bf16_t* __restrict__ Bm,
                                               OutT* __restrict__ C,
                                               int M, int N, int K) {
    __shared__ bf16_t As[3][128 * 32];   // 3 x 8KB
    __shared__ bf16_t Bs[3][128 * 32];
    int tid = threadIdx.x;
    int w = tid >> 6, l = tid & 63;
    int lr = l & 15, lk = l >> 4;
    int wr = (w >> 1) * 64, wc = (w & 1) * 64;
    int m0 = blockIdx.y * 128, n0 = blockIdx.x * 128;

    int srow = tid >> 2, sch = tid & 3;   // 64 rows/pass x 4 chunks(16B), 2 passes
    auto stage = [&](int buf, int kt) {
        int k0 = kt * 32;
        bf16_t* as = As[buf];
        bf16_t* bs = Bs[buf];
#pragma unroll
        for (int p = 0; p < 2; ++p) {
            int r = p * 64 + srow;
            int cs = ((sch ^ (r & 3)) << 3);
            gload16(&A[(size_t)(m0 + r) * K + k0 + cs], &as[p * 2048 + tid * 8]);
            gload16(&Bm[(size_t)(n0 + r) * K + k0 + cs], &bs[p * 2048 + tid * 8]);
        }
    };

    f32x4 acc[4][4] = {};
    int nk = K >> 5;
    stage(0, 0);
    stage(1, 1);
    int c0 = 0;
    int rsw = ((lk ^ (lr & 3)) << 3);     // read swizzle (R&3 == lr&3)
    for (int kt = 0; kt < nk; ++kt) {
        if (kt + 1 < nk) asm volatile("s_waitcnt vmcnt(4)" ::: "memory");
        else             asm volatile("s_waitcnt vmcnt(0)" ::: "memory");
        __builtin_amdgcn_s_barrier();
        __builtin_amdgcn_sched_barrier(0);
        if (kt + 2 < nk) stage(c0 == 0 ? 2 : c0 - 1, kt + 2);
        const bf16_t* as = As[c0];
        const bf16_t* bs = Bs[c0];
        bf16x8 af[4], bfr[4];
#pragma unroll
        for (int mm = 0; mm < 4; ++mm) af[mm]  = *(const bf16x8*)&as[(wr + mm * 16 + lr) * 32 + rsw];
#pragma unroll
        for (int nn = 0; nn < 4; ++nn) bfr[nn] = *(const bf16x8*)&bs[(wc + nn * 16 + lr) * 32 + rsw];
#pragma unroll
        for (int mm = 0; mm < 4; ++mm)
#pragma unroll
            for (int nn = 0; nn < 4; ++nn)
                acc[mm][nn] = __builtin_amdgcn_mfma_f32_16x16x32_bf16(af[mm], bfr[nn], acc[mm][nn], 0, 0, 0);
        c0 = (c0 == 2) ? 0 : c0 + 1;
    }
#pragma unroll
    for (int mm = 0; mm < 4; ++mm)
#pragma unroll
        for (int nn = 0; nn < 4; ++nn)
#pragma unroll
            for (int i = 0; i < 4; ++i) {
                int r = m0 + wr + mm * 16 + lk * 4 + i;
                int c = n0 + wc + nn * 16 + lr;
                C[(size_t)r * N + c] = (OutT)acc[mm][nn][i];
            }
}

// ---------------------------------------------------------------- fused QKV GEMM
// Same depth-2/3-buffer counted-vmcnt pipeline; Cs (32KB) unions over the
// first 32KB of the buffer space (live only after the post-loop barrier).
// Epilogue: RMSNorm+RoPE(table) or V-transpose.
__global__ __launch_bounds__(256) void gemm_qkv(const bf16_t* __restrict__ A,
                                                const bf16_t* __restrict__ Bm,
                                                const float* __restrict__ qnw,
                                                const float* __restrict__ knw,
                                                const float* __restrict__ ct,
                                                const float* __restrict__ st,
                                                bf16_t* __restrict__ qhm,
                                                bf16_t* __restrict__ khm,
                                                bf16_t* __restrict__ vtm) {
    __shared__ __align__(16) char smem_[49152];
    const int K = D_;
    int tid = threadIdx.x;
    int w = tid >> 6, l = tid & 63;
    int lr = l & 15, lk = l >> 4;
    int wr = (w >> 1) * 64, wc = (w & 1) * 64;
    int m0 = blockIdx.y * 128, n0 = blockIdx.x * 128;
    int hb = blockIdx.x;                // head-block: 0-15 Q, 16-23 K, 24-31 V

    int srow = tid >> 2, sch = tid & 3;
    auto stage = [&](int buf, int kt) {
        int k0 = kt * 32;
        bf16_t* as = (bf16_t*)(smem_ + buf * 8192);
        bf16_t* bs = (bf16_t*)(smem_ + 24576 + buf * 8192);
#pragma unroll
        for (int p = 0; p < 2; ++p) {
            int r = p * 64 + srow;
            int cs = ((sch ^ (r & 3)) << 3);
            gload16(&A[(size_t)(m0 + r) * K + k0 + cs], &as[p * 2048 + tid * 8]);
            gload16(&Bm[(size_t)(n0 + r) * K + k0 + cs], &bs[p * 2048 + tid * 8]);
        }
    };

    f32x4 acc[4][4] = {};
    const int nk = K >> 5;
    stage(0, 0);
    stage(1, 1);
    int c0 = 0;
    int rsw = ((lk ^ (lr & 3)) << 3);
    for (int kt = 0; kt < nk; ++kt) {
        if (kt + 1 < nk) asm volatile("s_waitcnt vmcnt(4)" ::: "memory");
        else             asm volatile("s_waitcnt vmcnt(0)" ::: "memory");
        __builtin_amdgcn_s_barrier();
        __builtin_amdgcn_sched_barrier(0);
        if (kt + 2 < nk) stage(c0 == 0 ? 2 : c0 - 1, kt + 2);
        const bf16_t* as = (const bf16_t*)(smem_ + c0 * 8192);
        const bf16_t* bs = (const bf16_t*)(smem_ + 24576 + c0 * 8192);
        bf16x8 af[4], bfr[4];
#pragma unroll
        for (int mm = 0; mm < 4; ++mm) af[mm]  = *(const bf16x8*)&as[(wr + mm * 16 + lr) * 32 + rsw];
#pragma unroll
        for (int nn = 0; nn < 4; ++nn) bfr[nn] = *(const bf16x8*)&bs[(wc + nn * 16 + lr) * 32 + rsw];
#pragma unroll
        for (int mm = 0; mm < 4; ++mm)
#pragma unroll
            for (int nn = 0; nn < 4; ++nn)
                acc[mm][nn] = __builtin_amdgcn_mfma_f32_16x16x32_bf16(af[mm], bfr[nn], acc[mm][nn], 0, 0, 0);
        c0 = (c0 == 2) ? 0 : c0 + 1;
    }
    __syncthreads();                       // all waves done with buffers -> Cs may overwrite
    bf16_t* Cs = (bf16_t*)smem_;           // [128*128], epilogue only

    // C -> LDS (union space), 16B-chunk XOR swizzle: chunk' = chunk ^ (row & 7)
#pragma unroll
    for (int mm = 0; mm < 4; ++mm)
#pragma unroll
        for (int nn = 0; nn < 4; ++nn)
#pragma unroll
            for (int i = 0; i < 4; ++i) {
                int r = wr + mm * 16 + lk * 4 + i;
                int c = wc + nn * 16 + lr;
                Cs[r * 128 + (((c >> 3) ^ (r & 7)) << 3) + (c & 7)] = (bf16_t)acc[mm][nn][i];
            }
    __syncthreads();

    int b = m0 >> 11, s0 = m0 & (S_ - 1);

    if (hb < 24) {
        // Q/K: per-head RMSNorm + RoPE (table), head-major store
        const float* nw = (hb < 16) ? qnw : knw;
        float scale = (hb < 16) ? SCALE_LOG2E_ : 1.0f;
        bf16_t* dst = (hb < 16)
            ? qhm + (((size_t)(b * H_ + hb)) * S_ + s0) * HD_
            : khm + (((size_t)(b * KVH_ + (hb - 16))) * S_ + s0) * HD_;
        int r = tid >> 1, hf = tid & 1;
        int rx = r & 7;
        float ss = 0.f;
#pragma unroll
        for (int c = 0; c < 8; ++c) {
            int cc = hf * 8 + c;
            bf16x8 v = *(const bf16x8*)&Cs[r * 128 + ((cc ^ rx) << 3)];
#pragma unroll
            for (int k = 0; k < 8; ++k) { float f = (float)v[k]; ss += f * f; }
        }
        ss += __shfl_xor(ss, 1);
        float rms = rsqrtf(ss * (1.0f / 128.0f) + 1e-6f);
        const float* ctr = ct + (size_t)(s0 + r) * 64;
        const float* str = st + (size_t)(s0 + r) * 64;
#pragma unroll
        for (int c = 0; c < 8; ++c) {
            int cc = hf * 8 + c;
            bf16x8 own = *(const bf16x8*)&Cs[r * 128 + ((cc ^ rx) << 3)];
            bf16x8 oth = *(const bf16x8*)&Cs[r * 128 + (((cc ^ 8) ^ rx) << 3)];
            f32x4 cv0 = *(const f32x4*)&ctr[c * 8];
            f32x4 cv1 = *(const f32x4*)&ctr[c * 8 + 4];
            f32x4 sv0 = *(const f32x4*)&str[c * 8];
            f32x4 sv1 = *(const f32x4*)&str[c * 8 + 4];
            bf16x8 o;
#pragma unroll
            for (int k = 0; k < 8; ++k) {
                int j = c * 8 + k;   // frequency index
                float xo = (float)own[k] * rms * nw[hf * 64 + j];
                float xr = (float)oth[k] * rms * nw[(hf ^ 1) * 64 + j];
                float co = (k < 4) ? cv0[k & 3] : cv1[k & 3];
                float si = (k < 4) ? sv0[k & 3] : sv1[k & 3];
                float val = hf ? (xo * co + xr * si) : (xo * co - xr * si);
                o[k] = (bf16_t)(val * scale);
            }
            *(bf16x8*)&dst[(size_t)r * HD_ + hf * 64 + c * 8] = o;
        }
    } else {
        // V: transpose to [b][kvh][d][S]
        int kv = hb - 24;
        bf16_t* vdst = vtm + (((size_t)(b * KVH_ + kv)) * HD_) * S_;
        int d = tid >> 1, sh = tid & 1;
        int dch = d >> 3, dlo = d & 7;
#pragma unroll
        for (int c = 0; c < 8; ++c) {
            bf16x8 o;
#pragma unroll
            for (int k = 0; k < 8; ++k) {
                int row = sh * 64 + c * 8 + k;
                o[k] = Cs[row * 128 + ((dch ^ (row & 7)) << 3) + dlo];
            }
            *(bf16x8*)&vdst[(size_t)d * S_ + s0 + sh * 64 + c * 8] = o;
        }
    }
}

// ---------------------------------------------------------------- flash attention
// 8-wave blocks, QBLK=128 (wave w owns rows q0+16w..+15), KBLK=64.
// Swapped QK^T (S^T = mfma(K,Q)) -> each lane holds one q-row (q=lr).
// CONSTANT-SHIFT softmax: scores are provably bounded (|v| <= scale*log2e*128
// = 16.34 since RMSNorm fixes ||q||=||k||=sqrt(128), RoPE is norm-preserving),
// so P = exp2(v) directly — no running max, no rescale, mathematically exact.
// cvt_pk + ds_bpermute P->bf16 repack; PV as O^T = mfma(V^T, P^T); dbuf staging.
__global__ __launch_bounds__(512, 4) void attn_fwd(const bf16_t* __restrict__ qh,
                                                   const bf16_t* __restrict__ kh,
                                                   const bf16_t* __restrict__ vt,
                                                   bf16_t* __restrict__ out) {
    int qt = (S_ / 128 - 1) - blockIdx.x;     // 0..15, longest first
    int bh = blockIdx.y;
    int b = bh >> 4, h = bh & 15, kvh = h >> 1;
    int tid = threadIdx.x, w = tid >> 6, l = tid & 63;
    int lr = l & 15, lk = l >> 4;
    int q0 = qt * 128;
    int esw = (lr & 7) << 3;                  // element-granularity XOR swizzle

    __shared__ bf16_t Ks[2][64 * 128];  // [k][d], XOR-swizzled rows (2x16KB)
    __shared__ bf16_t Vs[2][128 * 64];  // [d][k], XOR-swizzled rows (2x16KB)

    const bf16_t* kbase = kh + ((size_t)(b * KVH_ + kvh) * S_) * HD_;
    const bf16_t* vbase = vt + ((size_t)(b * KVH_ + kvh) * HD_) * S_;

    int krow = tid >> 4, kch = tid & 15;   // K: 32 rows/pass x 16 chunks(16B)
    int vrow = tid >> 3, vch = tid & 7;    // V: 64 rows/pass x 8 chunks(16B)
    int dst0 = w * 512 + l * 8;            // linear LDS dest (elements)

    // pre-swizzled global source, linear LDS dest; 2 gload16 each for K and V
    auto stage = [&](int buf, int k0) {
#pragma unroll
        for (int p = 0; p < 2; ++p) {
            int kr = krow + p * 32;
            gload16(kbase + (size_t)(k0 + kr) * HD_ + ((kch * 8) ^ ((kr & 7) << 3)),
                    &Ks[buf][dst0 + p * 4096]);
            int vr = vrow + p * 64;
            gload16(vbase + (size_t)vr * S_ + k0 + ((vch * 8) ^ ((vr & 7) << 3)),
                    &Vs[buf][dst0 + p * 4096]);
        }
    };

    bf16x8 qf[4];   // B-frag: Q[q=base+lr][d = c*32 + lk*8 + j]
    {
        const bf16_t* qbase = qh + ((size_t)(b * H_ + h) * S_ + q0 + w * 16 + lr) * HD_;
#pragma unroll
        for (int c = 0; c < 4; ++c)
            qf[c] = *(const bf16x8*)(qbase + c * 32 + lk * 8);
    }

    f32x4 acc[8] = {};                     // O^T[d = dt*16+lk*4+i][q=lr]
    float l_s = 0.f;                       // per-lane row-sum partial (q=lr)

    int grow_min = q0 + w * 16;            // wave's first q-row
    int gmax = grow_min + 15;              // wave's last q-row
    int qv = grow_min + lr;                // this lane's q-row
    int nkt = 2 * qt + 2;

    // bpermute source lanes (byte indices): holder lane = srcgrp*16 + lr
    int sA = (((lk & 1) << 5) + lr) << 2;  // srcgrp = 2*(lk&1)
    int sB = sA + 64;                      // srcgrp + 1
    bool lo = (lk < 2);                    // selects n = lk>>1

    stage(0, 0);                           // prologue: tile 0 -> buf A

    int cur = 0;
    for (int kt = 0; kt < nkt; ++kt) {
        int k0 = kt * 64;
        __syncthreads();                   // drains prefetch kt; orders reads of kt-1
        if (kt + 1 < nkt) stage(cur ^ 1, k0 + 64);   // prefetch under compute
        const bf16_t* ks = Ks[cur];
        const bf16_t* vs = Vs[cur];

        if (k0 <= gmax) {                  // wave-uniform: skip tiles above our rows
            // S^T = K·Q^T: lane holds p[n][i] = S[k=k0+16n+4lk+i][q=lr] (log2 domain)
            f32x4 p[4] = {};
            __builtin_amdgcn_s_setprio(1);
#pragma unroll
            for (int n = 0; n < 4; ++n) {
                int rbase = (n * 16 + lr) * 128;
#pragma unroll
                for (int c = 0; c < 4; ++c) {
                    bf16x8 kf = *(const bf16x8*)&ks[rbase + ((c * 32 + lk * 8) ^ esw)];
                    p[n] = __builtin_amdgcn_mfma_f32_16x16x32_bf16(kf, qf[c], p[n], 0, 0, 0);
                }
            }
            __builtin_amdgcn_s_setprio(0);

            if (k0 + 63 > grow_min) {      // causal mask on diagonal tile
                int kb = k0 + 4 * lk - qv; // masked iff kb + 16n + i > 0
#pragma unroll
                for (int n = 0; n < 4; ++n)
#pragma unroll
                    for (int i = 0; i < 4; ++i)
                        if (kb + 16 * n + i > 0) p[n][i] = -3e38f;
            }

            // exact constant-shift softmax: P = exp2(v); masked -> exp2(-3e38)=0
            float rs = 0.f;
#pragma unroll
            for (int n = 0; n < 4; ++n)
#pragma unroll
                for (int i = 0; i < 4; ++i) {
                    p[n][i] = EXP2F(p[n][i]);
                    rs += p[n][i];
                }
            l_s += rs;

            // pack P to bf16 dwords: cnv[n][c2] = (P[k=16n+4lk+2c2], P[+1]) @ q=lr
            unsigned cnv[4][2];
#pragma unroll
            for (int n = 0; n < 4; ++n) {
                asm("v_cvt_pk_bf16_f32 %0, %1, %2" : "=v"(cnv[n][0]) : "v"(p[n][0]), "v"(p[n][1]));
                asm("v_cvt_pk_bf16_f32 %0, %1, %2" : "=v"(cnv[n][1]) : "v"(p[n][2]), "v"(p[n][3]));
            }
            // exchange via bpermute: target (lk,lr) dword j2 of pf0 holds
            // P[q=lr][k=8lk+2j2,+1] = cnv[lk>>1][j2&1] @ lane (2*(lk&1)+(j2>>1), lr)
            u32x4 t0, t1;
            {
                unsigned a0 = bperm(sA, cnv[0][0]), b0 = bperm(sA, cnv[1][0]);
                unsigned a1 = bperm(sA, cnv[0][1]), b1 = bperm(sA, cnv[1][1]);
                unsigned a2 = bperm(sB, cnv[0][0]), b2 = bperm(sB, cnv[1][0]);
                unsigned a3 = bperm(sB, cnv[0][1]), b3 = bperm(sB, cnv[1][1]);
                t0.x = lo ? a0 : b0; t0.y = lo ? a1 : b1;
                t0.z = lo ? a2 : b2; t0.w = lo ? a3 : b3;
                unsigned c0 = bperm(sA, cnv[2][0]), d0 = bperm(sA, cnv[3][0]);
                unsigned c1 = bperm(sA, cnv[2][1]), d1 = bperm(sA, cnv[3][1]);
                unsigned c2 = bperm(sB, cnv[2][0]), d2 = bperm(sB, cnv[3][0]);
                unsigned c3 = bperm(sB, cnv[2][1]), d3 = bperm(sB, cnv[3][1]);
                t1.x = lo ? c0 : d0; t1.y = lo ? c1 : d1;
                t1.z = lo ? c2 : d2; t1.w = lo ? c3 : d3;
            }
            bf16x8 pf0 = __builtin_bit_cast(bf16x8, t0);
            bf16x8 pf1 = __builtin_bit_cast(bf16x8, t1);

            // O^T += V^T · P^T : A-frag = Vs rows (d), B-frag = pf
            __builtin_amdgcn_s_setprio(1);
#pragma unroll
            for (int dt = 0; dt < 8; ++dt) {
                int vb = (dt * 16 + lr) * 64;
                bf16x8 vf0 = *(const bf16x8*)&vs[vb + ((lk * 8) ^ esw)];
                acc[dt] = __builtin_amdgcn_mfma_f32_16x16x32_bf16(vf0, pf0, acc[dt], 0, 0, 0);
                bf16x8 vf1 = *(const bf16x8*)&vs[vb + ((32 + lk * 8) ^ esw)];
                acc[dt] = __builtin_amdgcn_mfma_f32_16x16x32_bf16(vf1, pf1, acc[dt], 0, 0, 0);
            }
            __builtin_amdgcn_s_setprio(0);
        }
        cur ^= 1;
    }

    // epilogue: l-reduce across lk groups, write O[q][d] as bf16x4
    float ls = l_s;
    ls += __shfl_xor(ls, 16);
    ls += __shfl_xor(ls, 32);
    float rl = 1.0f / ls;
    int s = grow_min + lr;
    bf16_t* ob = out + (((size_t)b * S_ + s) * H_ + h) * HD_;
#pragma unroll
    for (int dt = 0; dt < 8; ++dt) {
        bf16x4 o;
#pragma unroll
        for (int i = 0; i < 4; ++i) o[i] = (bf16_t)(acc[dt][i] * rl);
        *(bf16x4*)&ob[dt * 16 + lk * 4] = o;
    }
}

// ---------------------------------------------------------------- launch
extern "C" void kernel_launch(void* const* d_in, const int* in_sizes, int n_in,
                              void* d_out, int out_size, void* d_ws, size_t ws_size,
                              hipStream_t stream) {
    const float* x   = (const float*)d_in[0];
    const float* Wq  = (const float*)d_in[1];
    const float* Wk  = (const float*)d_in[2];
    const float* Wv  = (const float*)d_in[3];
    const float* Wo  = (const float*)d_in[4];
    const float* qnw = (const float*)d_in[5];
    const float* knw = (const float*)d_in[6];
    float* outp = (float*)d_out;

    char* ws = (char*)d_ws;
    size_t off = 0;
    auto alloc = [&](size_t bytes) -> void* {
        void* p = ws + off;
        off += (bytes + 255) & ~(size_t)255;
        return p;
    };
    bf16_t* xb    = (bf16_t*)alloc((size_t)TOK_ * D_ * 2);
    bf16_t* wqkvb = (bf16_t*)alloc((size_t)2 * D_ * D_ * 2);   // Wq|Wk|Wv rows
    bf16_t* wob   = (bf16_t*)alloc((size_t)D_ * D_ * 2);
    bf16_t* qhm   = (bf16_t*)alloc((size_t)TOK_ * D_ * 2);
    bf16_t* khm   = (bf16_t*)alloc((size_t)TOK_ * KVH_ * HD_ * 2);
    bf16_t* vtm   = (bf16_t*)alloc((size_t)TOK_ * KVH_ * HD_ * 2);
    bf16_t* attn  = (bf16_t*)alloc((size_t)TOK_ * D_ * 2);
    float*  ctab  = (float*)alloc((size_t)S_ * 64 * 4);
    float*  stab  = (float*)alloc((size_t)S_ * 64 * 4);
    (void)ws_size; (void)in_sizes; (void)n_in; (void)out_size;

    // fused converts + RoPE tables (one launch)
    fused_pre<<<CVT_BLKS_ + (S_ * 64) / 256, 256, 0, stream>>>(
        x, Wq, Wk, Wv, Wo, xb, wqkvb, wob, ctab, stab);

    // fused QKV projection + RMSNorm + RoPE(table) + head-major scatter + V transpose
    gemm_qkv<<<dim3((2 * D_) / 128, TOK_ / 128), 256, 0, stream>>>(
        xb, wqkvb, qnw, knw, ctab, stab, qhm, khm, vtm);

    // attention (8-wave blocks, QBLK=128, constant-shift exact softmax)
    attn_fwd<<<dim3(S_ / 128, B_ * H_), 512, 0, stream>>>(qhm, khm, vtm, attn);

    // output projection (f32 out)
    gemm_bt<float><<<dim3(D_ / 128, TOK_ / 128), 256, 0, stream>>>(attn, wob, outp, TOK_, D_, D_);
}

// Round 17
// 224.896 us; speedup vs baseline: 1.1007x; 1.1007x over previous
//
#include <hip/hip_runtime.h>
#include <hip/hip_bf16.h>

// Problem constants (B,S,D,H,KVH,HD) = (2,2048,2048,16,8,128)
#define B_   2
#define S_   2048
#define D_   2048
#define H_   16
#define KVH_ 8
#define HD_  128
#define TOK_ (B_ * S_)        // 4096 rows
#define KVSZ_ (KVH_ * HD_ * D_)
#define SCALE_LOG2E_ (0.08838834764831845f * 1.4426950408889634f)

typedef __bf16 bf16_t;
typedef bf16_t bf16x8 __attribute__((ext_vector_type(8)));
typedef bf16_t bf16x4 __attribute__((ext_vector_type(4)));
typedef float  f32x4  __attribute__((ext_vector_type(4)));
typedef unsigned int u32x4 __attribute__((ext_vector_type(4)));

#if __has_builtin(__builtin_amdgcn_exp2f)
#define EXP2F(x) __builtin_amdgcn_exp2f(x)
#else
#define EXP2F(x) exp2f(x)
#endif

// async global->LDS, 16B per lane (LDS dest = wave-uniform base + lane*16)
__device__ __forceinline__ void gload16(const bf16_t* g, bf16_t* l) {
    auto* gp = (const __attribute__((address_space(1))) unsigned int*)(g);
    auto* lp = (__attribute__((address_space(3))) unsigned int*)(l);
    __builtin_amdgcn_global_load_lds(gp, lp, 16, 0, 0);
}

// well-defined pull: dst[l] = src[byte_index[l] >> 2]
__device__ __forceinline__ unsigned bperm(int lane_bytes, unsigned src) {
    return (unsigned)__builtin_amdgcn_ds_bpermute(lane_bytes, (int)src);
}

// ---------------------------------------------------------------- fused pre-pass
// One launch: f32->bf16 converts (x, Wq|Wk|Wv packed, Wo) + RoPE tables.
#define CVT_BLKS_ ((TOK_ * D_ + 2 * D_ * D_ + 2 * KVSZ_) / 1024)
__global__ __launch_bounds__(256) void fused_pre(const float* __restrict__ x,
                                                 const float* __restrict__ Wq,
                                                 const float* __restrict__ Wk,
                                                 const float* __restrict__ Wv,
                                                 const float* __restrict__ Wo,
                                                 bf16_t* __restrict__ xb,
                                                 bf16_t* __restrict__ wqkvb,
                                                 bf16_t* __restrict__ wob,
                                                 float* __restrict__ ct,
                                                 float* __restrict__ st) {
    int bid = blockIdx.x;
    if (bid < CVT_BLKS_) {
        size_t i = (size_t)bid * 1024 + (size_t)threadIdx.x * 4;
        const size_t c0 = (size_t)TOK_ * D_;
        const size_t c1 = c0 + (size_t)D_ * D_;
        const size_t c2 = c1 + (size_t)KVSZ_;
        const size_t c3 = c2 + (size_t)KVSZ_;
        const float* src;
        bf16_t* dst;
        if (i < c0)      { src = x  + i;        dst = xb + i; }
        else if (i < c1) { src = Wq + (i - c0); dst = wqkvb + (i - c0); }
        else if (i < c2) { src = Wk + (i - c1); dst = wqkvb + (size_t)D_ * D_ + (i - c1); }
        else if (i < c3) { src = Wv + (i - c2); dst = wqkvb + (size_t)D_ * D_ + KVSZ_ + (i - c2); }
        else             { src = Wo + (i - c3); dst = wob + (i - c3); }
        float4 v = *(const float4*)src;
        bf16x4 o;
        o[0] = (bf16_t)v.x; o[1] = (bf16_t)v.y; o[2] = (bf16_t)v.z; o[3] = (bf16_t)v.w;
        *(bf16x4*)dst = o;
    } else {
        int i = (bid - CVT_BLKS_) * 256 + threadIdx.x;   // < S_*64
        int s = i >> 6, j = i & 63;
        float ang = (float)s * exp2f(-(float)j * 0.20762050593046013f);
        float si, co;
        sincosf(ang, &si, &co);
        ct[i] = co;
        st[i] = si;
    }
}

// ---------------------------------------------------------------- GEMM C = A * B^T
// Depth-1 dbuf staging (round-14 proven): one barrier/tile, prefetch kt+1
// flies under tile kt's MFMAs. BK=64, chunk-XOR ^(r&7) swizzled LDS.
template <typename OutT>
__global__ __launch_bounds__(256) void gemm_bt(const bf16_t* __restrict__ A,
                                               const bf16_t* __restrict__ Bm,
                                               OutT* __restrict__ C,
                                               int M, int N, int K) {
    __shared__ bf16_t As[2][128 * 64];
    __shared__ bf16_t Bs[2][128 * 64];
    int tid = threadIdx.x;
    int w = tid >> 6, l = tid & 63;
    int lr = l & 15, lk = l >> 4;
    int wr = (w >> 1) * 64, wc = (w & 1) * 64;
    int m0 = blockIdx.y * 128, n0 = blockIdx.x * 128;

    int srow = tid >> 3, sch = tid & 7;    // 32 rows/pass x 8 chunks(16B)
    auto stage = [&](int buf, int k0) {
        bf16_t* as = buf ? As[1] : As[0];
        bf16_t* bs = buf ? Bs[1] : Bs[0];
#pragma unroll
        for (int p = 0; p < 4; ++p) {
            int r = p * 32 + srow;
            int cs = ((sch ^ (r & 7)) << 3);
            gload16(&A[(size_t)(m0 + r) * K + k0 + cs], &as[p * 2048 + tid * 8]);
            gload16(&Bm[(size_t)(n0 + r) * K + k0 + cs], &bs[p * 2048 + tid * 8]);
        }
    };

    f32x4 acc[4][4] = {};
    int nk = K >> 6;
    stage(0, 0);                           // prologue: tile 0 -> buf 0
    int cur = 0;
    for (int kt = 0; kt < nk; ++kt) {
        __syncthreads();                   // drains prefetch kt; retires reads of kt-1
        if (kt + 1 < nk) stage(cur ^ 1, (kt + 1) * 64);
        const bf16_t* as = cur ? As[1] : As[0];
        const bf16_t* bs = cur ? Bs[1] : Bs[0];
#pragma unroll
        for (int kk = 0; kk < 2; ++kk) {
            bf16x8 af[4], bfr[4];
#pragma unroll
            for (int mm = 0; mm < 4; ++mm)
                af[mm] = *(const bf16x8*)&as[(wr + mm * 16 + lr) * 64 + (((kk * 4 + lk) ^ (lr & 7)) << 3)];
#pragma unroll
            for (int nn = 0; nn < 4; ++nn)
                bfr[nn] = *(const bf16x8*)&bs[(wc + nn * 16 + lr) * 64 + (((kk * 4 + lk) ^ (lr & 7)) << 3)];
#pragma unroll
            for (int mm = 0; mm < 4; ++mm)
#pragma unroll
                for (int nn = 0; nn < 4; ++nn)
                    acc[mm][nn] = __builtin_amdgcn_mfma_f32_16x16x32_bf16(af[mm], bfr[nn], acc[mm][nn], 0, 0, 0);
        }
        cur ^= 1;
    }
#pragma unroll
    for (int mm = 0; mm < 4; ++mm)
#pragma unroll
        for (int nn = 0; nn < 4; ++nn)
#pragma unroll
            for (int i = 0; i < 4; ++i) {
                int r = m0 + wr + mm * 16 + lk * 4 + i;
                int c = n0 + wc + nn * 16 + lr;
                C[(size_t)r * N + c] = (OutT)acc[mm][nn][i];
            }
}

// ---------------------------------------------------------------- fused QKV GEMM
// Depth-1 dbuf staging; Cs UNIONED over the As dbuf region (live only after
// the post-loop barrier). Epilogue: RMSNorm+RoPE(table) or V-transpose.
__global__ __launch_bounds__(256) void gemm_qkv(const bf16_t* __restrict__ A,
                                                const bf16_t* __restrict__ Bm,
                                                const float* __restrict__ qnw,
                                                const float* __restrict__ knw,
                                                const float* __restrict__ ct,
                                                const float* __restrict__ st,
                                                bf16_t* __restrict__ qhm,
                                                bf16_t* __restrict__ khm,
                                                bf16_t* __restrict__ vtm) {
    __shared__ __align__(16) char smem_[65536];
    bf16_t* As0 = (bf16_t*)smem_;              // [128*64]
    bf16_t* As1 = (bf16_t*)(smem_ + 16384);
    bf16_t* Bs0 = (bf16_t*)(smem_ + 32768);
    bf16_t* Bs1 = (bf16_t*)(smem_ + 49152);
    bf16_t* Cs  = (bf16_t*)smem_;              // [128*128], epilogue only
    const int K = D_;
    int tid = threadIdx.x;
    int w = tid >> 6, l = tid & 63;
    int lr = l & 15, lk = l >> 4;
    int wr = (w >> 1) * 64, wc = (w & 1) * 64;
    int m0 = blockIdx.y * 128, n0 = blockIdx.x * 128;
    int hb = blockIdx.x;                // head-block: 0-15 Q, 16-23 K, 24-31 V

    int srow = tid >> 3, sch = tid & 7;
    auto stage = [&](int buf, int k0) {
        bf16_t* as = buf ? As1 : As0;
        bf16_t* bs = buf ? Bs1 : Bs0;
#pragma unroll
        for (int p = 0; p < 4; ++p) {
            int r = p * 32 + srow;
            int cs = ((sch ^ (r & 7)) << 3);
            gload16(&A[(size_t)(m0 + r) * K + k0 + cs], &as[p * 2048 + tid * 8]);
            gload16(&Bm[(size_t)(n0 + r) * K + k0 + cs], &bs[p * 2048 + tid * 8]);
        }
    };

    f32x4 acc[4][4] = {};
    stage(0, 0);
    int cur = 0;
    for (int kt = 0; kt < (K >> 6); ++kt) {
        __syncthreads();                   // drains prefetch kt; retires reads of kt-1
        if (kt + 1 < (K >> 6)) stage(cur ^ 1, (kt + 1) * 64);
        const bf16_t* as = cur ? As1 : As0;
        const bf16_t* bs = cur ? Bs1 : Bs0;
#pragma unroll
        for (int kk = 0; kk < 2; ++kk) {
            bf16x8 af[4], bfr[4];
#pragma unroll
            for (int mm = 0; mm < 4; ++mm)
                af[mm] = *(const bf16x8*)&as[(wr + mm * 16 + lr) * 64 + (((kk * 4 + lk) ^ (lr & 7)) << 3)];
#pragma unroll
            for (int nn = 0; nn < 4; ++nn)
                bfr[nn] = *(const bf16x8*)&bs[(wc + nn * 16 + lr) * 64 + (((kk * 4 + lk) ^ (lr & 7)) << 3)];
#pragma unroll
            for (int mm = 0; mm < 4; ++mm)
#pragma unroll
                for (int nn = 0; nn < 4; ++nn)
                    acc[mm][nn] = __builtin_amdgcn_mfma_f32_16x16x32_bf16(af[mm], bfr[nn], acc[mm][nn], 0, 0, 0);
        }
        cur ^= 1;
    }
    __syncthreads();                       // all waves' last-tile reads done -> Cs may overwrite

    // C -> LDS (union space), 16B-chunk XOR swizzle: chunk' = chunk ^ (row & 7)
#pragma unroll
    for (int mm = 0; mm < 4; ++mm)
#pragma unroll
        for (int nn = 0; nn < 4; ++nn)
#pragma unroll
            for (int i = 0; i < 4; ++i) {
                int r = wr + mm * 16 + lk * 4 + i;
                int c = wc + nn * 16 + lr;
                Cs[r * 128 + (((c >> 3) ^ (r & 7)) << 3) + (c & 7)] = (bf16_t)acc[mm][nn][i];
            }
    __syncthreads();

    int b = m0 >> 11, s0 = m0 & (S_ - 1);

    if (hb < 24) {
        // Q/K: per-head RMSNorm + RoPE (table), head-major store
        const float* nw = (hb < 16) ? qnw : knw;
        float scale = (hb < 16) ? SCALE_LOG2E_ : 1.0f;
        bf16_t* dst = (hb < 16)
            ? qhm + (((size_t)(b * H_ + hb)) * S_ + s0) * HD_
            : khm + (((size_t)(b * KVH_ + (hb - 16))) * S_ + s0) * HD_;
        int r = tid >> 1, hf = tid & 1;
        int rx = r & 7;
        float ss = 0.f;
#pragma unroll
        for (int c = 0; c < 8; ++c) {
            int cc = hf * 8 + c;
            bf16x8 v = *(const bf16x8*)&Cs[r * 128 + ((cc ^ rx) << 3)];
#pragma unroll
            for (int k = 0; k < 8; ++k) { float f = (float)v[k]; ss += f * f; }
        }
        ss += __shfl_xor(ss, 1);
        float rms = rsqrtf(ss * (1.0f / 128.0f) + 1e-6f);
        const float* ctr = ct + (size_t)(s0 + r) * 64;
        const float* str = st + (size_t)(s0 + r) * 64;
#pragma unroll
        for (int c = 0; c < 8; ++c) {
            int cc = hf * 8 + c;
            bf16x8 own = *(const bf16x8*)&Cs[r * 128 + ((cc ^ rx) << 3)];
            bf16x8 oth = *(const bf16x8*)&Cs[r * 128 + (((cc ^ 8) ^ rx) << 3)];
            f32x4 cv0 = *(const f32x4*)&ctr[c * 8];
            f32x4 cv1 = *(const f32x4*)&ctr[c * 8 + 4];
            f32x4 sv0 = *(const f32x4*)&str[c * 8];
            f32x4 sv1 = *(const f32x4*)&str[c * 8 + 4];
            bf16x8 o;
#pragma unroll
            for (int k = 0; k < 8; ++k) {
                int j = c * 8 + k;   // frequency index
                float xo = (float)own[k] * rms * nw[hf * 64 + j];
                float xr = (float)oth[k] * rms * nw[(hf ^ 1) * 64 + j];
                float co = (k < 4) ? cv0[k & 3] : cv1[k & 3];
                float si = (k < 4) ? sv0[k & 3] : sv1[k & 3];
                float val = hf ? (xo * co + xr * si) : (xo * co - xr * si);
                o[k] = (bf16_t)(val * scale);
            }
            *(bf16x8*)&dst[(size_t)r * HD_ + hf * 64 + c * 8] = o;
        }
    } else {
        // V: transpose to [b][kvh][d][S]
        int kv = hb - 24;
        bf16_t* vdst = vtm + (((size_t)(b * KVH_ + kv)) * HD_) * S_;
        int d = tid >> 1, sh = tid & 1;
        int dch = d >> 3, dlo = d & 7;
#pragma unroll
        for (int c = 0; c < 8; ++c) {
            bf16x8 o;
#pragma unroll
            for (int k = 0; k < 8; ++k) {
                int row = sh * 64 + c * 8 + k;
                o[k] = Cs[row * 128 + ((dch ^ (row & 7)) << 3) + dlo];
            }
            *(bf16x8*)&vdst[(size_t)d * S_ + s0 + sh * 64 + c * 8] = o;
        }
    }
}

// ---------------------------------------------------------------- flash attention
// 8-wave blocks, QBLK=128 (wave w owns rows q0+16w..+15), KBLK=64.
// Swapped QK^T (S^T = mfma(K,Q)) -> each lane holds one q-row (q=lr).
// CONSTANT-SHIFT softmax: scores are provably bounded (|v| <= scale*log2e*128
// = 16.34 since RMSNorm fixes ||q||=||k||=sqrt(128), RoPE is norm-preserving),
// so P = exp2(v) directly — no running max, no rescale, mathematically exact.
// cvt_pk + ds_bpermute P->bf16 repack; PV as O^T = mfma(V^T, P^T); dbuf staging.
__global__ __launch_bounds__(512, 4) void attn_fwd(const bf16_t* __restrict__ qh,
                                                   const bf16_t* __restrict__ kh,
                                                   const bf16_t* __restrict__ vt,
                                                   bf16_t* __restrict__ out) {
    int qt = (S_ / 128 - 1) - blockIdx.x;     // 0..15, longest first
    int bh = blockIdx.y;
    int b = bh >> 4, h = bh & 15, kvh = h >> 1;
    int tid = threadIdx.x, w = tid >> 6, l = tid & 63;
    int lr = l & 15, lk = l >> 4;
    int q0 = qt * 128;
    int esw = (lr & 7) << 3;                  // element-granularity XOR swizzle

    __shared__ bf16_t Ks[2][64 * 128];  // [k][d], XOR-swizzled rows (2x16KB)
    __shared__ bf16_t Vs[2][128 * 64];  // [d][k], XOR-swizzled rows (2x16KB)

    const bf16_t* kbase = kh + ((size_t)(b * KVH_ + kvh) * S_) * HD_;
    const bf16_t* vbase = vt + ((size_t)(b * KVH_ + kvh) * HD_) * S_;

    int krow = tid >> 4, kch = tid & 15;   // K: 32 rows/pass x 16 chunks(16B)
    int vrow = tid >> 3, vch = tid & 7;    // V: 64 rows/pass x 8 chunks(16B)
    int dst0 = w * 512 + l * 8;            // linear LDS dest (elements)

    // pre-swizzled global source, linear LDS dest; 2 gload16 each for K and V
    auto stage = [&](int buf, int k0) {
#pragma unroll
        for (int p = 0; p < 2; ++p) {
            int kr = krow + p * 32;
            gload16(kbase + (size_t)(k0 + kr) * HD_ + ((kch * 8) ^ ((kr & 7) << 3)),
                    &Ks[buf][dst0 + p * 4096]);
            int vr = vrow + p * 64;
            gload16(vbase + (size_t)vr * S_ + k0 + ((vch * 8) ^ ((vr & 7) << 3)),
                    &Vs[buf][dst0 + p * 4096]);
        }
    };

    bf16x8 qf[4];   // B-frag: Q[q=base+lr][d = c*32 + lk*8 + j]
    {
        const bf16_t* qbase = qh + ((size_t)(b * H_ + h) * S_ + q0 + w * 16 + lr) * HD_;
#pragma unroll
        for (int c = 0; c < 4; ++c)
            qf[c] = *(const bf16x8*)(qbase + c * 32 + lk * 8);
    }

    f32x4 acc[8] = {};                     // O^T[d = dt*16+lk*4+i][q=lr]
    float l_s = 0.f;                       // per-lane row-sum partial (q=lr)

    int grow_min = q0 + w * 16;            // wave's first q-row
    int gmax = grow_min + 15;              // wave's last q-row
    int qv = grow_min + lr;                // this lane's q-row
    int nkt = 2 * qt + 2;

    // bpermute source lanes (byte indices): holder lane = srcgrp*16 + lr
    int sA = (((lk & 1) << 5) + lr) << 2;  // srcgrp = 2*(lk&1)
    int sB = sA + 64;                      // srcgrp + 1
    bool lo = (lk < 2);                    // selects n = lk>>1

    stage(0, 0);                           // prologue: tile 0 -> buf A

    int cur = 0;
    for (int kt = 0; kt < nkt; ++kt) {
        int k0 = kt * 64;
        __syncthreads();                   // drains prefetch kt; orders reads of kt-1
        if (kt + 1 < nkt) stage(cur ^ 1, k0 + 64);   // prefetch under compute
        const bf16_t* ks = Ks[cur];
        const bf16_t* vs = Vs[cur];

        if (k0 <= gmax) {                  // wave-uniform: skip tiles above our rows
            // S^T = K·Q^T: lane holds p[n][i] = S[k=k0+16n+4lk+i][q=lr] (log2 domain)
            f32x4 p[4] = {};
            __builtin_amdgcn_s_setprio(1);
#pragma unroll
            for (int n = 0; n < 4; ++n) {
                int rbase = (n * 16 + lr) * 128;
#pragma unroll
                for (int c = 0; c < 4; ++c) {
                    bf16x8 kf = *(const bf16x8*)&ks[rbase + ((c * 32 + lk * 8) ^ esw)];
                    p[n] = __builtin_amdgcn_mfma_f32_16x16x32_bf16(kf, qf[c], p[n], 0, 0, 0);
                }
            }
            __builtin_amdgcn_s_setprio(0);

            if (k0 + 63 > grow_min) {      // causal mask on diagonal tile
                int kb = k0 + 4 * lk - qv; // masked iff kb + 16n + i > 0
#pragma unroll
                for (int n = 0; n < 4; ++n)
#pragma unroll
                    for (int i = 0; i < 4; ++i)
                        if (kb + 16 * n + i > 0) p[n][i] = -3e38f;
            }

            // exact constant-shift softmax: P = exp2(v); masked -> exp2(-3e38)=0
            float rs = 0.f;
#pragma unroll
            for (int n = 0; n < 4; ++n)
#pragma unroll
                for (int i = 0; i < 4; ++i) {
                    p[n][i] = EXP2F(p[n][i]);
                    rs += p[n][i];
                }
            l_s += rs;

            // pack P to bf16 dwords: cnv[n][c2] = (P[k=16n+4lk+2c2], P[+1]) @ q=lr
            unsigned cnv[4][2];
#pragma unroll
            for (int n = 0; n < 4; ++n) {
                asm("v_cvt_pk_bf16_f32 %0, %1, %2" : "=v"(cnv[n][0]) : "v"(p[n][0]), "v"(p[n][1]));
                asm("v_cvt_pk_bf16_f32 %0, %1, %2" : "=v"(cnv[n][1]) : "v"(p[n][2]), "v"(p[n][3]));
            }
            // exchange via bpermute: target (lk,lr) dword j2 of pf0 holds
            // P[q=lr][k=8lk+2j2,+1] = cnv[lk>>1][j2&1] @ lane (2*(lk&1)+(j2>>1), lr)
            u32x4 t0, t1;
            {
                unsigned a0 = bperm(sA, cnv[0][0]), b0 = bperm(sA, cnv[1][0]);
                unsigned a1 = bperm(sA, cnv[0][1]), b1 = bperm(sA, cnv[1][1]);
                unsigned a2 = bperm(sB, cnv[0][0]), b2 = bperm(sB, cnv[1][0]);
                unsigned a3 = bperm(sB, cnv[0][1]), b3 = bperm(sB, cnv[1][1]);
                t0.x = lo ? a0 : b0; t0.y = lo ? a1 : b1;
                t0.z = lo ? a2 : b2; t0.w = lo ? a3 : b3;
                unsigned c0 = bperm(sA, cnv[2][0]), d0 = bperm(sA, cnv[3][0]);
                unsigned c1 = bperm(sA, cnv[2][1]), d1 = bperm(sA, cnv[3][1]);
                unsigned c2 = bperm(sB, cnv[2][0]), d2 = bperm(sB, cnv[3][0]);
                unsigned c3 = bperm(sB, cnv[2][1]), d3 = bperm(sB, cnv[3][1]);
                t1.x = lo ? c0 : d0; t1.y = lo ? c1 : d1;
                t1.z = lo ? c2 : d2; t1.w = lo ? c3 : d3;
            }
            bf16x8 pf0 = __builtin_bit_cast(bf16x8, t0);
            bf16x8 pf1 = __builtin_bit_cast(bf16x8, t1);

            // O^T += V^T · P^T : A-frag = Vs rows (d), B-frag = pf
            __builtin_amdgcn_s_setprio(1);
#pragma unroll
            for (int dt = 0; dt < 8; ++dt) {
                int vb = (dt * 16 + lr) * 64;
                bf16x8 vf0 = *(const bf16x8*)&vs[vb + ((lk * 8) ^ esw)];
                acc[dt] = __builtin_amdgcn_mfma_f32_16x16x32_bf16(vf0, pf0, acc[dt], 0, 0, 0);
                bf16x8 vf1 = *(const bf16x8*)&vs[vb + ((32 + lk * 8) ^ esw)];
                acc[dt] = __builtin_amdgcn_mfma_f32_16x16x32_bf16(vf1, pf1, acc[dt], 0, 0, 0);
            }
            __builtin_amdgcn_s_setprio(0);
        }
        cur ^= 1;
    }

    // epilogue: l-reduce across lk groups, write O[q][d] as bf16x4
    float ls = l_s;
    ls += __shfl_xor(ls, 16);
    ls += __shfl_xor(ls, 32);
    float rl = 1.0f / ls;
    int s = grow_min + lr;
    bf16_t* ob = out + (((size_t)b * S_ + s) * H_ + h) * HD_;
#pragma unroll
    for (int dt = 0; dt < 8; ++dt) {
        bf16x4 o;
#pragma unroll
        for (int i = 0; i < 4; ++i) o[i] = (bf16_t)(acc[dt][i] * rl);
        *(bf16x4*)&ob[dt * 16 + lk * 4] = o;
    }
}

// ---------------------------------------------------------------- launch
extern "C" void kernel_launch(void* const* d_in, const int* in_sizes, int n_in,
                              void* d_out, int out_size, void* d_ws, size_t ws_size,
                              hipStream_t stream) {
    const float* x   = (const float*)d_in[0];
    const float* Wq  = (const float*)d_in[1];
    const float* Wk  = (const float*)d_in[2];
    const float* Wv  = (const float*)d_in[3];
    const float* Wo  = (const float*)d_in[4];
    const float* qnw = (const float*)d_in[5];
    const float* knw = (const float*)d_in[6];
    float* outp = (float*)d_out;

    char* ws = (char*)d_ws;
    size_t off = 0;
    auto alloc = [&](size_t bytes) -> void* {
        void* p = ws + off;
        off += (bytes + 255) & ~(size_t)255;
        return p;
    };
    bf16_t* xb    = (bf16_t*)alloc((size_t)TOK_ * D_ * 2);
    bf16_t* wqkvb = (bf16_t*)alloc((size_t)2 * D_ * D_ * 2);   // Wq|Wk|Wv rows
    bf16_t* wob   = (bf16_t*)alloc((size_t)D_ * D_ * 2);
    bf16_t* qhm   = (bf16_t*)alloc((size_t)TOK_ * D_ * 2);
    bf16_t* khm   = (bf16_t*)alloc((size_t)TOK_ * KVH_ * HD_ * 2);
    bf16_t* vtm   = (bf16_t*)alloc((size_t)TOK_ * KVH_ * HD_ * 2);
    bf16_t* attn  = (bf16_t*)alloc((size_t)TOK_ * D_ * 2);
    float*  ctab  = (float*)alloc((size_t)S_ * 64 * 4);
    float*  stab  = (float*)alloc((size_t)S_ * 64 * 4);
    (void)ws_size; (void)in_sizes; (void)n_in; (void)out_size;

    // fused converts + RoPE tables (one launch)
    fused_pre<<<CVT_BLKS_ + (S_ * 64) / 256, 256, 0, stream>>>(
        x, Wq, Wk, Wv, Wo, xb, wqkvb, wob, ctab, stab);

    // fused QKV projection + RMSNorm + RoPE(table) + head-major scatter + V transpose
    gemm_qkv<<<dim3((2 * D_) / 128, TOK_ / 128), 256, 0, stream>>>(
        xb, wqkvb, qnw, knw, ctab, stab, qhm, khm, vtm);

    // attention (8-wave blocks, QBLK=128, constant-shift exact softmax)
    attn_fwd<<<dim3(S_ / 128, B_ * H_), 512, 0, stream>>>(qhm, khm, vtm, attn);

    // output projection (f32 out)
    gemm_bt<float><<<dim3(D_ / 128, TOK_ / 128), 256, 0, stream>>>(attn, wob, outp, TOK_, D_, D_);
}